// Round 9
// baseline (121.963 us; speedup 1.0000x reference)
//
#include <hip/hip_runtime.h>

typedef __attribute__((ext_vector_type(8))) short bf16x8;
typedef __attribute__((ext_vector_type(4))) float f32x4;

#define T_SEQ 1024
#define NH 16
#define CEMB 1024

__device__ __forceinline__ float asf(unsigned int u){ union{unsigned int i;float f;}x; x.i=u; return x.f; }
__device__ __forceinline__ float bf2f(unsigned short u){ return asf(((unsigned int)u)<<16); }
__device__ __forceinline__ unsigned short f2bf(float f){
  union{float f;unsigned int i;}x; x.f=f;
  unsigned int r = x.i + 0x7FFFu + ((x.i>>16)&1u);
  return (unsigned short)(r>>16);
}
__device__ __forceinline__ f32x4 MFMA16(bf16x8 a, bf16x8 b, f32x4 c){
  return __builtin_amdgcn_mfma_f32_16x16x32_bf16(a, b, c, 0,0,0);
}

// ---------------- fused: x -> x_bf16  AND  gates = softmax(x @ Wgate + bgate) ----------------
__global__ __launch_bounds__(256)
void prep_kernel(const float* __restrict__ x, const float* __restrict__ Wg,
                 const float* __restrict__ bg, unsigned short* __restrict__ x_bf,
                 float* __restrict__ gates){
  const int lane = threadIdx.x & 63;
  const int row  = blockIdx.x*4 + (threadIdx.x>>6);
  const float4* xr = reinterpret_cast<const float4*>(x + (size_t)row*CEMB);
  ushort4* xbr = reinterpret_cast<ushort4*>(x_bf + (size_t)row*CEMB);
  float acc[NH];
  #pragma unroll
  for (int h=0;h<NH;h++) acc[h]=0.f;
  #pragma unroll
  for (int i=0;i<4;i++){
    float4 v = xr[i*64 + lane];
    ushort4 o; o.x=f2bf(v.x); o.y=f2bf(v.y); o.z=f2bf(v.z); o.w=f2bf(v.w);
    xbr[i*64 + lane] = o;
    #pragma unroll
    for (int j=0;j<4;j++){
      const float xv = (j==0)?v.x:(j==1)?v.y:(j==2)?v.z:v.w;
      const float4* wg = reinterpret_cast<const float4*>(Wg + (size_t)(i*256 + lane*4 + j)*NH);
      float4 a=wg[0], b=wg[1], c=wg[2], d=wg[3];
      acc[0]+=xv*a.x; acc[1]+=xv*a.y; acc[2]+=xv*a.z; acc[3]+=xv*a.w;
      acc[4]+=xv*b.x; acc[5]+=xv*b.y; acc[6]+=xv*b.z; acc[7]+=xv*b.w;
      acc[8]+=xv*c.x; acc[9]+=xv*c.y; acc[10]+=xv*c.z; acc[11]+=xv*c.w;
      acc[12]+=xv*d.x; acc[13]+=xv*d.y; acc[14]+=xv*d.z; acc[15]+=xv*d.w;
    }
  }
  #pragma unroll
  for (int h=0;h<NH;h++){
    #pragma unroll
    for (int m=32;m;m>>=1) acc[h] += __shfl_xor(acc[h], m, 64);
  }
  float mx = -1e30f;
  #pragma unroll
  for (int h=0;h<NH;h++){ acc[h] += bg[h]; mx = fmaxf(mx, acc[h]); }
  float s = 0.f;
  #pragma unroll
  for (int h=0;h<NH;h++){ acc[h] = __expf(acc[h]-mx); s += acc[h]; }
  float g = 0.f;
  #pragma unroll
  for (int h=0;h<NH;h++) g = (lane==h) ? acc[h]/s : g;
  if (lane < NH) gates[(size_t)row*NH + lane] = g;
}

// ---------------- both weight transposes, one launch (blockIdx-partitioned) ----------------
__global__ void wtrans_kernel(const float* __restrict__ Wqk, unsigned short* __restrict__ WqkT,
                              const float* __restrict__ Wproj, unsigned short* __restrict__ WprojT){
  __shared__ float tile[32][33];
  int blk = blockIdx.x;
  const float* W; unsigned short* Wt; int R, C, bx, by;
  if (blk < 2048){ W = Wqk;   Wt = WqkT;   R = 1024; C = 2048; bx = blk & 63; by = blk >> 6; }
  else { blk -= 2048; W = Wproj; Wt = WprojT; R = 1024; C = 1024; bx = blk & 31; by = blk >> 5; }
  const int c0 = bx*32, r0 = by*32;
  const int tx = threadIdx.x, ty = threadIdx.y;   // (32,8)
  #pragma unroll
  for (int i=0;i<32;i+=8) tile[ty+i][tx] = W[(size_t)(r0+ty+i)*C + c0 + tx];
  __syncthreads();
  #pragma unroll
  for (int i=0;i<32;i+=8) Wt[(size_t)(c0+ty+i)*R + r0 + tx] = f2bf(tile[tx][ty+i]);
}

// ---------------- bf16 MFMA GEMM: C[M][N] = A[M][K] @ Bt[N][K]^T + bias ----------------
// Double-buffered stage-ahead (2-phase) + XCD-aware block swizzle (grid%8==0).
template<bool OUT_BF16>
__global__ __launch_bounds__(256)
void gemm_bt_kernel(const unsigned short* __restrict__ A, const unsigned short* __restrict__ Bt,
                    const float* __restrict__ bias, void* __restrict__ Cptr,
                    int M, int N, int K){
  __shared__ unsigned short lA0[128*64], lA1[128*64];
  __shared__ unsigned short lB0[128*64], lB1[128*64];
  const int tid = threadIdx.x;
  const int wid = tid>>6, lane = tid&63;
  const int nbm = M>>7;
  // XCD swizzle: contiguous chunk of blocks per XCD (bijective; gridDim.x % 8 == 0)
  int bid = blockIdx.x;
  const int cpx = gridDim.x >> 3;
  bid = (bid & 7)*cpx + (bid >> 3);
  const int bm = bid % nbm, bn = bid / nbm;
  const int wr = wid>>1, wc = wid&1;
  f32x4 acc[4][4] = {};

  const unsigned short* gA = A + (size_t)bm*128*K;
  const unsigned short* gB = Bt + (size_t)bn*128*K;
  const int srow = lane>>3;
  const int schunk = lane&7;

#define GSTAGE(LA, LB, KK) do { \
  _Pragma("unroll") \
  for (int i_=0;i_<4;i_++){ \
    int rowi_ = (wid*4+i_)*8 + srow; \
    int cc_ = schunk ^ (rowi_ & 7); \
    __builtin_amdgcn_global_load_lds((const __attribute__((address_space(1))) void*)(gA + (size_t)rowi_*K + (KK) + cc_*8), \
        (__attribute__((address_space(3))) void*)&LA[(wid*4+i_)*512], 16, 0, 0); \
    __builtin_amdgcn_global_load_lds((const __attribute__((address_space(1))) void*)(gB + (size_t)rowi_*K + (KK) + cc_*8), \
        (__attribute__((address_space(3))) void*)&LB[(wid*4+i_)*512], 16, 0, 0); \
  } \
} while(0)

#define GCOMPUTE(LA, LB) do { \
  _Pragma("unroll") \
  for (int ks_=0; ks_<2; ks_++){ \
    bf16x8 af_[4], bf_[4]; \
    _Pragma("unroll") \
    for (int m_=0;m_<4;m_++){ \
      int r_ = wr*64 + m_*16 + (lane&15); \
      int p_ = (ks_*4 + (lane>>4)) ^ (r_&7); \
      af_[m_] = *reinterpret_cast<const bf16x8*>(&LA[r_*64 + p_*8]); \
    } \
    _Pragma("unroll") \
    for (int n_=0;n_<4;n_++){ \
      int r_ = wc*64 + n_*16 + (lane&15); \
      int p_ = (ks_*4 + (lane>>4)) ^ (r_&7); \
      bf_[n_] = *reinterpret_cast<const bf16x8*>(&LB[r_*64 + p_*8]); \
    } \
    _Pragma("unroll") \
    for (int m_=0;m_<4;m_++) \
      _Pragma("unroll") \
      for (int n_=0;n_<4;n_++) \
        acc[m_][n_] = __builtin_amdgcn_mfma_f32_16x16x32_bf16(af_[m_], bf_[n_], acc[m_][n_], 0,0,0); \
  } \
} while(0)

  GSTAGE(lA0, lB0, 0);
  __syncthreads();
  for (int k0=0; k0<K; k0+=128){
    GSTAGE(lA1, lB1, k0+64);     // issue next-half loads, no wait
    GCOMPUTE(lA0, lB0);          // MFMA on current (hides stage latency)
    __syncthreads();             // drain (after compute) + publish lA1/lB1
    if (k0+128 < K) GSTAGE(lA0, lB0, k0+128);
    GCOMPUTE(lA1, lB1);
    __syncthreads();
  }
#undef GSTAGE
#undef GCOMPUTE

  const int rq = lane>>4;
  const int cl = lane&15;
  #pragma unroll
  for (int n=0;n<4;n++){
    int col = bn*128 + wc*64 + n*16 + cl;
    float bv = bias[col];
    #pragma unroll
    for (int m=0;m<4;m++){
      int row = bm*128 + wr*64 + m*16 + rq*4;
      #pragma unroll
      for (int r=0;r<4;r++){
        float v = acc[m][n][r] + bv;
        if (OUT_BF16) ((unsigned short*)Cptr)[(size_t)(row+r)*N + col] = f2bf(v);
        else          ((float*)Cptr)[(size_t)(row+r)*N + col] = v;
      }
    }
  }
}

// ---------------- fragment pack: K rows -> Kpack (QK B-frags) + Vpack (PV B-frags) ----------------
__global__ __launch_bounds__(256)
void kpack_kernel(const unsigned short* __restrict__ qk,
                  unsigned short* __restrict__ Kpack, unsigned short* __restrict__ Vpack){
  __shared__ unsigned short lT[64][68];
  const int blk = blockIdx.x;          // 1024 = 64 bh * 16 tgroups
  const int t0 = (blk & 15) * 64;
  const int bh = blk >> 4;
  const int b = bh >> 4, h = bh & 15;
  const int tid = threadIdx.x;
  #pragma unroll
  for (int it=0; it<2; it++){
    int idx = tid + it*256;
    int row = idx >> 3, c = idx & 7;
    uint4 v = *reinterpret_cast<const uint4*>(qk + ((size_t)(b*T_SEQ + t0 + row)*2048 + 1024 + h*64 + c*8));
    *reinterpret_cast<uint4*>(&lT[row][c*8]) = v;
  }
  __syncthreads();
  const int wid = tid>>6, lane = tid&63;
  const int g = lane>>4, li = lane&15;
  const int tile = wid>>1;             // 0..1 (32-row tile within the 64 staged rows)
  const int kt = (t0>>5) + tile;
  #pragma unroll
  for (int ff=0; ff<2; ff++){
    const int f = (wid&1)*2 + ff;
    const int row = tile*32 + ((f>>1)<<4) + li;
    const int col = (f&1)*32 + g*8;
    uint4 v = *reinterpret_cast<const uint4*>(&lT[row][col]);
    *reinterpret_cast<uint4*>(Kpack + ((((size_t)bh*32 + kt)*4 + f)*64 + lane)*8) = v;
  }
  #pragma unroll
  for (int ff=0; ff<2; ff++){
    const int d4 = (wid&1)*2 + ff;
    unsigned short vv[8];
    #pragma unroll
    for (int j=0;j<8;j++) vv[j] = lT[tile*32 + g*8 + j][d4*16 + li];
    *reinterpret_cast<uint4*>(Vpack + ((((size_t)bh*32 + kt)*4 + d4)*64 + lane)*8) = *reinterpret_cast<const uint4*>(vv);
  }
}

// ---------------- split-K MFMA attention, no-max softmax, packed coalesced frags ----------------
__global__ __launch_bounds__(256)
void attn_mfma_kernel(const unsigned short* __restrict__ qk,
                      const unsigned short* __restrict__ Kpack,
                      const unsigned short* __restrict__ Vpack,
                      const float* __restrict__ gates, unsigned short* __restrict__ gated,
                      unsigned short* __restrict__ pO, float* __restrict__ pL){
  __shared__ unsigned short lP[4][16*40];
  const int tid = threadIdx.x;
  const int wid = tid>>6, lane = tid&63;
  const int g = lane>>4, li = lane&15;

  const int W = blockIdx.x*4 + wid;
  int h, c, b, qw16; bool partial;
  if (W < 1024){ h = 0; c = W>>8; int r = W&255; b = r>>6; qw16 = r&63; partial = true; }
  else if (W < 1536){ h = 1; int Wp = W-1024; c = Wp>>8; int r = Wp&255; b = r>>6; qw16 = r&63; partial = true; }
  else { int Wp = W-1536; h = 2 + (Wp>>8); int r = Wp&255; b = r>>6; qw16 = r&63; c = 0; partial = false; }

  int w = 1024 >> h; if (w < 4) w = 4;
  const int qw0 = qw16*16;
  const int bh = b*NH + h;

  int mylo = qw0 - w + 1; if (mylo < 0) mylo = 0;
  const int kt_lo_full = mylo >> 5;
  const int kt_hi_full = (qw0 + 15) >> 5;
  const int slot = (b*64 + qw16)*6 + ((h==0) ? c : 4 + c);

  int kt_start, kt_end;
  if (partial){
    const int CH = (h==0) ? 8 : 9;
    kt_end = kt_hi_full - c*CH;
    kt_start = kt_end - (CH-1); if (kt_start < kt_lo_full) kt_start = kt_lo_full;
    if (kt_end < kt_lo_full){
      unsigned short* po = pO + (size_t)slot*16*64;
      #pragma unroll
      for (int r2=0;r2<4;r2++){
        const int row = g*4 + r2;
        #pragma unroll
        for (int d4=0; d4<4; d4++) po[row*64 + d4*16 + li] = 0;
      }
      if (li == 0){
        #pragma unroll
        for (int r2=0;r2<4;r2++) pL[(size_t)slot*16 + g*4 + r2] = 0.f;
      }
      return;
    }
  } else {
    kt_start = kt_lo_full; kt_end = kt_hi_full;
  }

  // Q A-fragments (once per wave)
  const unsigned short* qbase = qk + ((size_t)(b*T_SEQ + qw0 + li)*2048 + h*64 + g*8);
  const bf16x8 aq0 = *reinterpret_cast<const bf16x8*>(qbase);
  const bf16x8 aq1 = *reinterpret_cast<const bf16x8*>(qbase + 32);

  f32x4 oacc[4] = {};
  float lsum[4] = {0.f,0.f,0.f,0.f};

  const unsigned short* kp = Kpack + (size_t)bh*32*4*512;
  const unsigned short* vp = Vpack + (size_t)bh*32*4*512;
  const int loff = lane*8;

  bf16x8 kf[4], kn[4], bv[4];
  #pragma unroll
  for (int f=0; f<4; f++)
    kf[f] = *reinterpret_cast<const bf16x8*>(kp + (kt_start*4 + f)*512 + loff);

  for (int kt = kt_start; kt <= kt_end; ++kt){
    // V frags (current tile), coalesced; issued early, consumed after exp
    #pragma unroll
    for (int d4=0; d4<4; d4++)
      bv[d4] = *reinterpret_cast<const bf16x8*>(vp + (kt*4 + d4)*512 + loff);
    // prefetch next K frags (clamped, branch-free)
    {
      const int ktn = (kt < kt_end) ? kt+1 : kt_end;
      #pragma unroll
      for (int f=0; f<4; f++)
        kn[f] = *reinterpret_cast<const bf16x8*>(kp + (ktn*4 + f)*512 + loff);
    }

    // ---- QK^T ----
    f32x4 s0 = {}, s1 = {};
    s0 = MFMA16(aq0, kf[0], s0);
    s0 = MFMA16(aq1, kf[1], s0);
    s1 = MFMA16(aq0, kf[2], s1);
    s1 = MFMA16(aq1, kf[3], s1);

    // ---- no-max softmax accumulate: p = valid ? exp(s/8) : 0 ----
    const int k0 = kt*32;
    #pragma unroll
    for (int r=0;r<4;r++){
      const int t = qw0 + g*4 + r;
      const int ka = k0 + li;
      const int kb2 = ka + 16;
      const bool v0 = (ka <= t) && (ka > t - w);
      const bool v1 = (kb2 <= t) && (kb2 > t - w);
      const float p0 = v0 ? __expf(s0[r]*0.125f) : 0.f;
      const float p1 = v1 ? __expf(s1[r]*0.125f) : 0.f;
      lsum[r] += p0 + p1;
      const int q = g*4 + r;
      lP[wid][q*40 + li]      = f2bf(p0);
      lP[wid][q*40 + 16 + li] = f2bf(p1);
    }
    // wave-local LDS bounce (lgkmcnt-ordered, no barrier)
    const bf16x8 pa = *reinterpret_cast<const bf16x8*>(&lP[wid][li*40 + g*8]);
    #pragma unroll
    for (int d4=0; d4<4; d4++)
      oacc[d4] = MFMA16(pa, bv[d4], oacc[d4]);
    #pragma unroll
    for (int i=0;i<4;i++) kf[i] = kn[i];
  }

  // one final cross-lane sum reduce over li (4 rounds)
  #pragma unroll
  for (int msk=1; msk<16; msk<<=1){
    #pragma unroll
    for (int r=0;r<4;r++) lsum[r] += __shfl_xor(lsum[r], msk, 64);
  }

  if (partial){
    unsigned short* po = pO + (size_t)slot*16*64;
    #pragma unroll
    for (int r2=0;r2<4;r2++){
      const int row = g*4 + r2;
      #pragma unroll
      for (int d4=0; d4<4; d4++) po[row*64 + d4*16 + li] = f2bf(oacc[d4][r2]);
    }
    if (li == 0){
      #pragma unroll
      for (int r2=0;r2<4;r2++) pL[(size_t)slot*16 + g*4 + r2] = lsum[r2];
    }
  } else {
    #pragma unroll
    for (int r=0;r<4;r++){
      const int t = qw0 + g*4 + r;
      const float gv = gates[(size_t)(b*T_SEQ + t)*NH + h];
      const float inv = gv / lsum[r];
      unsigned short* orow = gated + (size_t)(b*T_SEQ + t)*CEMB + h*64 + li;
      orow[0]  = f2bf(oacc[0][r]*inv);
      orow[16] = f2bf(oacc[1][r]*inv);
      orow[32] = f2bf(oacc[2][r]*inv);
      orow[48] = f2bf(oacc[3][r]*inv);
    }
  }
}

// ---------------- merge partials for h=0,1 (plain sums, no exp) ----------------
__global__ __launch_bounds__(256)
void attn_merge_kernel(const unsigned short* __restrict__ pO, const float* __restrict__ pL,
                       const float* __restrict__ gates, unsigned short* __restrict__ gated){
  const int wid = threadIdx.x>>6, lane = threadIdx.x&63;
  const int W = blockIdx.x*4 + wid;     // [0,512)
  const int h = W>>8;
  const int r = W&255;
  const int b = r>>6, qw16 = r&63;
  const int nch = (h==0) ? 4 : 2;
  const int sb  = (h==0) ? 0 : 4;
  const int slot0 = (b*64 + qw16)*6 + sb;
  for (int row=0; row<16; ++row){
    const int t = qw16*16 + row;
    float L = 0.f, acc = 0.f;
    #pragma unroll
    for (int c2=0;c2<4;c2++){
      if (c2 < nch){
        L   += pL[(size_t)(slot0+c2)*16 + row];
        acc += bf2f(pO[((size_t)(slot0+c2)*16 + row)*64 + lane]);
      }
    }
    const float gv = gates[(size_t)(b*T_SEQ + t)*NH + h];
    gated[(size_t)(b*T_SEQ + t)*CEMB + h*64 + lane] = f2bf(acc * gv / L);
  }
}

extern "C" void kernel_launch(void* const* d_in, const int* in_sizes, int n_in,
                              void* d_out, int out_size, void* d_ws, size_t ws_size,
                              hipStream_t stream){
  const float* x     = (const float*)d_in[0];
  const float* Wqk   = (const float*)d_in[1];
  const float* bqk   = (const float*)d_in[2];
  const float* Wgate = (const float*)d_in[3];
  const float* bgate = (const float*)d_in[4];
  const float* Wproj = (const float*)d_in[5];
  const float* bproj = (const float*)d_in[6];
  float* out = (float*)d_out;

  // workspace layout (~56MB of the 256MB ws)
  unsigned short* x_bf   = (unsigned short*)d_ws;                 // 8MB
  unsigned short* WqkT   = x_bf   + (size_t)4096*1024;            // 4MB
  unsigned short* WprojT = WqkT   + (size_t)2048*1024;            // 2MB
  unsigned short* qkb    = WprojT + (size_t)1024*1024;            // 16MB
  unsigned short* gated  = qkb    + (size_t)4096*2048;            // 8MB
  float*          gates  = (float*)(gated + (size_t)4096*1024);   // 256KB
  unsigned short* pO     = WqkT;                                  // alias (dead after gemm1)
  float*          pL     = (float*)(WqkT + (size_t)4*64*6*16*64);
  unsigned short* Kpack  = (unsigned short*)((char*)d_ws + (size_t)40*1024*1024);  // 8MB
  unsigned short* Vpack  = Kpack + (size_t)64*32*4*512;                            // 8MB

  prep_kernel<<<1024, 256, 0, stream>>>(x, Wgate, bgate, x_bf, gates);
  wtrans_kernel<<<3072, dim3(32,8), 0, stream>>>(Wqk, WqkT, Wproj, WprojT);

  gemm_bt_kernel<true ><<<512, 256, 0, stream>>>(x_bf,  WqkT,   bqk,   qkb, 4096, 2048, 1024);
  kpack_kernel<<<1024, 256, 0, stream>>>(qkb, Kpack, Vpack);
  attn_mfma_kernel<<<1280, 256, 0, stream>>>(qkb, Kpack, Vpack, gates, gated, pO, pL);
  attn_merge_kernel<<<128, 256, 0, stream>>>(pO, pL, gates, gated);
  gemm_bt_kernel<false><<<256, 256, 0, stream>>>(gated, WprojT, bproj, out, 4096, 1024, 1024);
}

// Round 10
// 110.934 us; speedup vs baseline: 1.0994x; 1.0994x over previous
//
#include <hip/hip_runtime.h>

typedef __attribute__((ext_vector_type(8))) short bf16x8;
typedef __attribute__((ext_vector_type(4))) float f32x4;

#define T_SEQ 1024
#define NH 16
#define CEMB 1024

__device__ __forceinline__ float asf(unsigned int u){ union{unsigned int i;float f;}x; x.i=u; return x.f; }
__device__ __forceinline__ float bf2f(unsigned short u){ return asf(((unsigned int)u)<<16); }
__device__ __forceinline__ unsigned short f2bf(float f){
  union{float f;unsigned int i;}x; x.f=f;
  unsigned int r = x.i + 0x7FFFu + ((x.i>>16)&1u);
  return (unsigned short)(r>>16);
}
__device__ __forceinline__ f32x4 MFMA16(bf16x8 a, bf16x8 b, f32x4 c){
  return __builtin_amdgcn_mfma_f32_16x16x32_bf16(a, b, c, 0,0,0);
}

// ---------------- fp32 -> bf16 convert (vectorized) ----------------
__global__ void cvt_bf16_kernel(const float* __restrict__ in, unsigned short* __restrict__ out, int n){
  int i = (blockIdx.x*blockDim.x + threadIdx.x)*4;
  if (i >= n) return;
  float4 v = *reinterpret_cast<const float4*>(in + i);
  ushort4 o; o.x=f2bf(v.x); o.y=f2bf(v.y); o.z=f2bf(v.z); o.w=f2bf(v.w);
  *reinterpret_cast<ushort4*>(out + i) = o;
}

// ---------------- gates: softmax(x @ Wgate + bgate) over H ----------------
__global__ void gates_kernel(const float* __restrict__ x, const float* __restrict__ Wg,
                             const float* __restrict__ bg, float* __restrict__ gates){
  const int lane = threadIdx.x & 63;
  const int row  = blockIdx.x*4 + (threadIdx.x>>6);
  const float* xr = x + (size_t)row*CEMB;
  float acc[NH];
  #pragma unroll
  for (int h=0;h<NH;h++) acc[h]=0.f;
  for (int i=0;i<CEMB/64;i++){
    float xv = xr[i*64 + lane];
    const float4* wg = reinterpret_cast<const float4*>(Wg + (size_t)(i*64+lane)*NH);
    float4 a=wg[0], b=wg[1], c=wg[2], d=wg[3];
    acc[0]+=xv*a.x; acc[1]+=xv*a.y; acc[2]+=xv*a.z; acc[3]+=xv*a.w;
    acc[4]+=xv*b.x; acc[5]+=xv*b.y; acc[6]+=xv*b.z; acc[7]+=xv*b.w;
    acc[8]+=xv*c.x; acc[9]+=xv*c.y; acc[10]+=xv*c.z; acc[11]+=xv*c.w;
    acc[12]+=xv*d.x; acc[13]+=xv*d.y; acc[14]+=xv*d.z; acc[15]+=xv*d.w;
  }
  #pragma unroll
  for (int h=0;h<NH;h++){
    #pragma unroll
    for (int m=32;m;m>>=1) acc[h] += __shfl_xor(acc[h], m, 64);
  }
  float mx = -1e30f;
  #pragma unroll
  for (int h=0;h<NH;h++){ acc[h] += bg[h]; mx = fmaxf(mx, acc[h]); }
  float s = 0.f;
  #pragma unroll
  for (int h=0;h<NH;h++){ acc[h] = __expf(acc[h]-mx); s += acc[h]; }
  float g = 0.f;
  #pragma unroll
  for (int h=0;h<NH;h++) g = (lane==h) ? acc[h]/s : g;
  if (lane < NH) gates[(size_t)row*NH + lane] = g;
}

// ---------------- both weight transposes, one launch (blockIdx-partitioned) ----------------
__global__ void wtrans_kernel(const float* __restrict__ Wqk, unsigned short* __restrict__ WqkT,
                              const float* __restrict__ Wproj, unsigned short* __restrict__ WprojT){
  __shared__ float tile[32][33];
  int blk = blockIdx.x;
  const float* W; unsigned short* Wt; int R, C, bx, by;
  if (blk < 2048){ W = Wqk;   Wt = WqkT;   R = 1024; C = 2048; bx = blk & 63; by = blk >> 6; }
  else { blk -= 2048; W = Wproj; Wt = WprojT; R = 1024; C = 1024; bx = blk & 31; by = blk >> 5; }
  const int c0 = bx*32, r0 = by*32;
  const int tx = threadIdx.x, ty = threadIdx.y;   // (32,8)
  #pragma unroll
  for (int i=0;i<32;i+=8) tile[ty+i][tx] = W[(size_t)(r0+ty+i)*C + c0 + tx];
  __syncthreads();
  #pragma unroll
  for (int i=0;i<32;i+=8) Wt[(size_t)(c0+ty+i)*R + r0 + tx] = f2bf(tile[tx][ty+i]);
}

// ---------------- bf16 MFMA GEMM: C[M][N] = A[M][K] @ Bt[N][K]^T + bias ----------------
// Double-buffered stage-ahead (2-phase). BM template: 128 (waves 2x2, 64x64 each)
// or 64 (waves 1x4, 64x32 each; 48KB LDS -> 3 blocks/CU for small-grid tails).
template<bool OUT_BF16, int BM>
__global__ __launch_bounds__(256)
void gemm_bt_kernel(const unsigned short* __restrict__ A, const unsigned short* __restrict__ Bt,
                    const float* __restrict__ bias, void* __restrict__ Cptr,
                    int M, int N, int K){
  constexpr int WCN   = (BM==128) ? 2 : 4;       // wave cols
  constexpr int MFRAG = (BM==128) ? 4 : 4;       // 16-row frags per wave
  constexpr int NFRAG = 4/(WCN/2);               // 128/WCN/16
  constexpr int WCW   = 128/WCN;                 // wave col width
  constexpr int AISS  = BM/32;                   // A stage issues
  __shared__ unsigned short lA0[BM*64], lA1[BM*64];
  __shared__ unsigned short lB0[128*64], lB1[128*64];
  const int tid = threadIdx.x;
  const int wid = tid>>6, lane = tid&63;
  const int nbm = M/BM;
  const int bid = blockIdx.x;
  const int bm = bid % nbm, bn = bid / nbm;
  const int wr = (BM==128) ? (wid>>1) : 0;
  const int wc = (BM==128) ? (wid&1) : wid;
  f32x4 acc[MFRAG][NFRAG] = {};

  const unsigned short* gA = A + (size_t)bm*BM*K;
  const unsigned short* gB = Bt + (size_t)bn*128*K;
  const int srow = lane>>3;
  const int schunk = lane&7;

#define GSTAGE(LA, LB, KK) do { \
  _Pragma("unroll") \
  for (int i_=0;i_<AISS;i_++){ \
    int rowi_ = (wid*AISS+i_)*8 + srow; \
    int cc_ = schunk ^ (rowi_ & 7); \
    __builtin_amdgcn_global_load_lds((const __attribute__((address_space(1))) void*)(gA + (size_t)rowi_*K + (KK) + cc_*8), \
        (__attribute__((address_space(3))) void*)&LA[(wid*AISS+i_)*512], 16, 0, 0); \
  } \
  _Pragma("unroll") \
  for (int i_=0;i_<4;i_++){ \
    int rowi_ = (wid*4+i_)*8 + srow; \
    int cc_ = schunk ^ (rowi_ & 7); \
    __builtin_amdgcn_global_load_lds((const __attribute__((address_space(1))) void*)(gB + (size_t)rowi_*K + (KK) + cc_*8), \
        (__attribute__((address_space(3))) void*)&LB[(wid*4+i_)*512], 16, 0, 0); \
  } \
} while(0)

#define GCOMPUTE(LA, LB) do { \
  _Pragma("unroll") \
  for (int ks_=0; ks_<2; ks_++){ \
    bf16x8 af_[MFRAG], bf_[NFRAG]; \
    _Pragma("unroll") \
    for (int m_=0;m_<MFRAG;m_++){ \
      int r_ = wr*64 + m_*16 + (lane&15); \
      int p_ = (ks_*4 + (lane>>4)) ^ (r_&7); \
      af_[m_] = *reinterpret_cast<const bf16x8*>(&LA[r_*64 + p_*8]); \
    } \
    _Pragma("unroll") \
    for (int n_=0;n_<NFRAG;n_++){ \
      int r_ = wc*WCW + n_*16 + (lane&15); \
      int p_ = (ks_*4 + (lane>>4)) ^ (r_&7); \
      bf_[n_] = *reinterpret_cast<const bf16x8*>(&LB[r_*64 + p_*8]); \
    } \
    _Pragma("unroll") \
    for (int m_=0;m_<MFRAG;m_++) \
      _Pragma("unroll") \
      for (int n_=0;n_<NFRAG;n_++) \
        acc[m_][n_] = __builtin_amdgcn_mfma_f32_16x16x32_bf16(af_[m_], bf_[n_], acc[m_][n_], 0,0,0); \
  } \
} while(0)

  GSTAGE(lA0, lB0, 0);
  __syncthreads();
  for (int k0=0; k0<K; k0+=128){
    GSTAGE(lA1, lB1, k0+64);     // issue next-half loads, no wait
    GCOMPUTE(lA0, lB0);          // MFMA on current (hides stage latency)
    __syncthreads();             // drain (after compute) + publish lA1/lB1
    if (k0+128 < K) GSTAGE(lA0, lB0, k0+128);
    GCOMPUTE(lA1, lB1);
    __syncthreads();
  }
#undef GSTAGE
#undef GCOMPUTE

  const int rq = lane>>4;
  const int cl = lane&15;
  #pragma unroll
  for (int n=0;n<NFRAG;n++){
    int col = bn*128 + wc*WCW + n*16 + cl;
    float bv = bias[col];
    #pragma unroll
    for (int m=0;m<MFRAG;m++){
      int row = bm*BM + wr*64 + m*16 + rq*4;
      #pragma unroll
      for (int r=0;r<4;r++){
        float v = acc[m][n][r] + bv;
        if (OUT_BF16) ((unsigned short*)Cptr)[(size_t)(row+r)*N + col] = f2bf(v);
        else          ((float*)Cptr)[(size_t)(row+r)*N + col] = v;
      }
    }
  }
}

// ---------------- fragment pack: K rows -> Kpack (QK B-frags) + Vpack (PV B-frags) ----------------
__global__ __launch_bounds__(256)
void kpack_kernel(const unsigned short* __restrict__ qk,
                  unsigned short* __restrict__ Kpack, unsigned short* __restrict__ Vpack){
  __shared__ unsigned short lT[64][68];
  const int blk = blockIdx.x;          // 1024 = 64 bh * 16 tgroups
  const int t0 = (blk & 15) * 64;
  const int bh = blk >> 4;
  const int b = bh >> 4, h = bh & 15;
  const int tid = threadIdx.x;
  #pragma unroll
  for (int it=0; it<2; it++){
    int idx = tid + it*256;
    int row = idx >> 3, c = idx & 7;
    uint4 v = *reinterpret_cast<const uint4*>(qk + ((size_t)(b*T_SEQ + t0 + row)*2048 + 1024 + h*64 + c*8));
    *reinterpret_cast<uint4*>(&lT[row][c*8]) = v;
  }
  __syncthreads();
  const int wid = tid>>6, lane = tid&63;
  const int g = lane>>4, li = lane&15;
  const int tile = wid>>1;             // 0..1 (32-row tile within the 64 staged rows)
  const int kt = (t0>>5) + tile;
  #pragma unroll
  for (int ff=0; ff<2; ff++){
    const int f = (wid&1)*2 + ff;
    const int row = tile*32 + ((f>>1)<<4) + li;
    const int col = (f&1)*32 + g*8;
    uint4 v = *reinterpret_cast<const uint4*>(&lT[row][col]);
    *reinterpret_cast<uint4*>(Kpack + ((((size_t)bh*32 + kt)*4 + f)*64 + lane)*8) = v;
  }
  #pragma unroll
  for (int ff=0; ff<2; ff++){
    const int d4 = (wid&1)*2 + ff;
    unsigned short vv[8];
    #pragma unroll
    for (int j=0;j<8;j++) vv[j] = lT[tile*32 + g*8 + j][d4*16 + li];
    *reinterpret_cast<uint4*>(Vpack + ((((size_t)bh*32 + kt)*4 + d4)*64 + lane)*8) = *reinterpret_cast<const uint4*>(vv);
  }
}

// ---------------- split-K MFMA attention, no-max softmax, packed coalesced frags ----------------
__global__ __launch_bounds__(256)
void attn_mfma_kernel(const unsigned short* __restrict__ qk,
                      const unsigned short* __restrict__ Kpack,
                      const unsigned short* __restrict__ Vpack,
                      const float* __restrict__ gates, unsigned short* __restrict__ gated,
                      unsigned short* __restrict__ pO, float* __restrict__ pL){
  __shared__ unsigned short lP[4][16*40];
  const int tid = threadIdx.x;
  const int wid = tid>>6, lane = tid&63;
  const int g = lane>>4, li = lane&15;

  const int W = blockIdx.x*4 + wid;
  int h, c, b, qw16; bool partial;
  if (W < 1024){ h = 0; c = W>>8; int r = W&255; b = r>>6; qw16 = r&63; partial = true; }
  else if (W < 1536){ h = 1; int Wp = W-1024; c = Wp>>8; int r = Wp&255; b = r>>6; qw16 = r&63; partial = true; }
  else { int Wp = W-1536; h = 2 + (Wp>>8); int r = Wp&255; b = r>>6; qw16 = r&63; c = 0; partial = false; }

  int w = 1024 >> h; if (w < 4) w = 4;
  const int qw0 = qw16*16;
  const int bh = b*NH + h;

  int mylo = qw0 - w + 1; if (mylo < 0) mylo = 0;
  const int kt_lo_full = mylo >> 5;
  const int kt_hi_full = (qw0 + 15) >> 5;
  const int slot = (b*64 + qw16)*6 + ((h==0) ? c : 4 + c);

  int kt_start, kt_end;
  if (partial){
    const int CH = (h==0) ? 8 : 9;
    kt_end = kt_hi_full - c*CH;
    kt_start = kt_end - (CH-1); if (kt_start < kt_lo_full) kt_start = kt_lo_full;
    if (kt_end < kt_lo_full){
      unsigned short* po = pO + (size_t)slot*16*64;
      #pragma unroll
      for (int r2=0;r2<4;r2++){
        const int row = g*4 + r2;
        #pragma unroll
        for (int d4=0; d4<4; d4++) po[row*64 + d4*16 + li] = 0;
      }
      if (li == 0){
        #pragma unroll
        for (int r2=0;r2<4;r2++) pL[(size_t)slot*16 + g*4 + r2] = 0.f;
      }
      return;
    }
  } else {
    kt_start = kt_lo_full; kt_end = kt_hi_full;
  }

  // Q A-fragments (once per wave)
  const unsigned short* qbase = qk + ((size_t)(b*T_SEQ + qw0 + li)*2048 + h*64 + g*8);
  const bf16x8 aq0 = *reinterpret_cast<const bf16x8*>(qbase);
  const bf16x8 aq1 = *reinterpret_cast<const bf16x8*>(qbase + 32);

  f32x4 oacc[4] = {};
  float lsum[4] = {0.f,0.f,0.f,0.f};

  const unsigned short* kp = Kpack + (size_t)bh*32*4*512;
  const unsigned short* vp = Vpack + (size_t)bh*32*4*512;
  const int loff = lane*8;

  bf16x8 kf[4], kn[4], bv[4];
  #pragma unroll
  for (int f=0; f<4; f++)
    kf[f] = *reinterpret_cast<const bf16x8*>(kp + (kt_start*4 + f)*512 + loff);

  for (int kt = kt_start; kt <= kt_end; ++kt){
    // V frags (current tile), coalesced; issued early, consumed after exp
    #pragma unroll
    for (int d4=0; d4<4; d4++)
      bv[d4] = *reinterpret_cast<const bf16x8*>(vp + (kt*4 + d4)*512 + loff);
    // prefetch next K frags (clamped, branch-free)
    {
      const int ktn = (kt < kt_end) ? kt+1 : kt_end;
      #pragma unroll
      for (int f=0; f<4; f++)
        kn[f] = *reinterpret_cast<const bf16x8*>(kp + (ktn*4 + f)*512 + loff);
    }

    // ---- QK^T ----
    f32x4 s0 = {}, s1 = {};
    s0 = MFMA16(aq0, kf[0], s0);
    s0 = MFMA16(aq1, kf[1], s0);
    s1 = MFMA16(aq0, kf[2], s1);
    s1 = MFMA16(aq1, kf[3], s1);

    // ---- no-max softmax accumulate: p = valid ? exp(s/8) : 0 ----
    const int k0 = kt*32;
    #pragma unroll
    for (int r=0;r<4;r++){
      const int t = qw0 + g*4 + r;
      const int ka = k0 + li;
      const int kb2 = ka + 16;
      const bool v0 = (ka <= t) && (ka > t - w);
      const bool v1 = (kb2 <= t) && (kb2 > t - w);
      const float p0 = v0 ? __expf(s0[r]*0.125f) : 0.f;
      const float p1 = v1 ? __expf(s1[r]*0.125f) : 0.f;
      lsum[r] += p0 + p1;
      const int q = g*4 + r;
      lP[wid][q*40 + li]      = f2bf(p0);
      lP[wid][q*40 + 16 + li] = f2bf(p1);
    }
    // wave-local LDS bounce (lgkmcnt-ordered, no barrier)
    const bf16x8 pa = *reinterpret_cast<const bf16x8*>(&lP[wid][li*40 + g*8]);
    #pragma unroll
    for (int d4=0; d4<4; d4++)
      oacc[d4] = MFMA16(pa, bv[d4], oacc[d4]);
    #pragma unroll
    for (int i=0;i<4;i++) kf[i] = kn[i];
  }

  // one final cross-lane sum reduce over li (4 rounds)
  #pragma unroll
  for (int msk=1; msk<16; msk<<=1){
    #pragma unroll
    for (int r=0;r<4;r++) lsum[r] += __shfl_xor(lsum[r], msk, 64);
  }

  if (partial){
    unsigned short* po = pO + (size_t)slot*16*64;
    #pragma unroll
    for (int r2=0;r2<4;r2++){
      const int row = g*4 + r2;
      #pragma unroll
      for (int d4=0; d4<4; d4++) po[row*64 + d4*16 + li] = f2bf(oacc[d4][r2]);
    }
    if (li == 0){
      #pragma unroll
      for (int r2=0;r2<4;r2++) pL[(size_t)slot*16 + g*4 + r2] = lsum[r2];
    }
  } else {
    #pragma unroll
    for (int r=0;r<4;r++){
      const int t = qw0 + g*4 + r;
      const float gv = gates[(size_t)(b*T_SEQ + t)*NH + h];
      const float inv = gv / lsum[r];
      unsigned short* orow = gated + (size_t)(b*T_SEQ + t)*CEMB + h*64 + li;
      orow[0]  = f2bf(oacc[0][r]*inv);
      orow[16] = f2bf(oacc[1][r]*inv);
      orow[32] = f2bf(oacc[2][r]*inv);
      orow[48] = f2bf(oacc[3][r]*inv);
    }
  }
}

// ---------------- merge partials for h=0,1 (plain sums, no exp) ----------------
__global__ __launch_bounds__(256)
void attn_merge_kernel(const unsigned short* __restrict__ pO, const float* __restrict__ pL,
                       const float* __restrict__ gates, unsigned short* __restrict__ gated){
  const int wid = threadIdx.x>>6, lane = threadIdx.x&63;
  const int W = blockIdx.x*4 + wid;     // [0,512)
  const int h = W>>8;
  const int r = W&255;
  const int b = r>>6, qw16 = r&63;
  const int nch = (h==0) ? 4 : 2;
  const int sb  = (h==0) ? 0 : 4;
  const int slot0 = (b*64 + qw16)*6 + sb;
  for (int row=0; row<16; ++row){
    const int t = qw16*16 + row;
    float L = 0.f, acc = 0.f;
    #pragma unroll
    for (int c2=0;c2<4;c2++){
      if (c2 < nch){
        L   += pL[(size_t)(slot0+c2)*16 + row];
        acc += bf2f(pO[((size_t)(slot0+c2)*16 + row)*64 + lane]);
      }
    }
    const float gv = gates[(size_t)(b*T_SEQ + t)*NH + h];
    gated[(size_t)(b*T_SEQ + t)*CEMB + h*64 + lane] = f2bf(acc * gv / L);
  }
}

extern "C" void kernel_launch(void* const* d_in, const int* in_sizes, int n_in,
                              void* d_out, int out_size, void* d_ws, size_t ws_size,
                              hipStream_t stream){
  const float* x     = (const float*)d_in[0];
  const float* Wqk   = (const float*)d_in[1];
  const float* bqk   = (const float*)d_in[2];
  const float* Wgate = (const float*)d_in[3];
  const float* bgate = (const float*)d_in[4];
  const float* Wproj = (const float*)d_in[5];
  const float* bproj = (const float*)d_in[6];
  float* out = (float*)d_out;

  // workspace layout (~56MB of the 256MB ws)
  unsigned short* x_bf   = (unsigned short*)d_ws;                 // 8MB
  unsigned short* WqkT   = x_bf   + (size_t)4096*1024;            // 4MB
  unsigned short* WprojT = WqkT   + (size_t)2048*1024;            // 2MB
  unsigned short* qkb    = WprojT + (size_t)1024*1024;            // 16MB
  unsigned short* gated  = qkb    + (size_t)4096*2048;            // 8MB
  float*          gates  = (float*)(gated + (size_t)4096*1024);   // 256KB
  unsigned short* pO     = WqkT;                                  // alias (dead after gemm1)
  float*          pL     = (float*)(WqkT + (size_t)4*64*6*16*64);
  unsigned short* Kpack  = (unsigned short*)((char*)d_ws + (size_t)40*1024*1024);  // 8MB
  unsigned short* Vpack  = Kpack + (size_t)64*32*4*512;                            // 8MB

  cvt_bf16_kernel<<<4096, 256, 0, stream>>>(x, x_bf, 4096*1024);
  wtrans_kernel<<<3072, dim3(32,8), 0, stream>>>(Wqk, WqkT, Wproj, WprojT);
  gates_kernel<<<1024, 256, 0, stream>>>(x, Wgate, bgate, gates);

  gemm_bt_kernel<true, 128><<<512, 256, 0, stream>>>(x_bf,  WqkT,   bqk,   qkb, 4096, 2048, 1024);
  kpack_kernel<<<1024, 256, 0, stream>>>(qkb, Kpack, Vpack);
  attn_mfma_kernel<<<1280, 256, 0, stream>>>(qkb, Kpack, Vpack, gates, gated, pO, pL);
  attn_merge_kernel<<<128, 256, 0, stream>>>(pO, pL, gates, gated);
  gemm_bt_kernel<false, 64><<<512, 256, 0, stream>>>(gated, WprojT, bproj, out, 4096, 1024, 1024);
}